// Round 9
// baseline (11893.201 us; speedup 1.0000x reference)
//
#include <hip/hip_runtime.h>
#include <stdint.h>

#define TT 128
#define BB 64
#define DD 1024
#define G3 3072

typedef unsigned short u16;
typedef unsigned int u32;
typedef __attribute__((ext_vector_type(8))) short bf16x8;
typedef __attribute__((ext_vector_type(4))) short s16x4;
typedef __attribute__((ext_vector_type(4))) float f32x4;

__device__ __forceinline__ float b2f(u16 h){ u32 u = ((u32)h)<<16; float f; __builtin_memcpy(&f,&u,4); return f; }
__device__ __forceinline__ u16 f2b(float f){ u32 u; __builtin_memcpy(&u,&f,4); u = (u + 0x7fffu + ((u>>16)&1u))>>16; return (u16)u; }
__device__ __forceinline__ float sigm(float x){ return 1.f/(1.f+__expf(-x)); }
__device__ __forceinline__ float tanh_(float x){
  if (x > 10.f) return 1.f;
  if (x < -10.f) return -1.f;
  float e = __expf(2.f*x); return (e-1.f)/(e+1.f);
}

struct DPar {
  const u16 *A1,*A2,*A3,*A4,*A5,*A6;   // bf16 weights
  const float* feat;
  u16 *ghist,*cb,*qselb,*qnewb,*eb0,*eb1;
  float *scoresP;                       // [TT][32][BB] per-block score partials
  float *parties,*gf,*ef,*GIPa,*GHP;
  const float *bihg,*bhhg,*bihp,*bhhp,*bihe,*bhhe,*watt;
  const int* spk;
  float* out;
};

// ---- A-fragment loaders (bf16 direct; fp32 converted in-flight) ----
__device__ __forceinline__ void loadA(bf16x8& d, const u16* p){ d = *(const bf16x8*)p; }
__device__ __forceinline__ void loadA(bf16x8& d, const float* p){
  f32x4 lo = *(const f32x4*)p;
  f32x4 hi = *(const f32x4*)(p + 4);
  #pragma unroll
  for (int i = 0; i < 4; ++i) { d[i] = (short)f2b(lo[i]); d[i+4] = (short)f2b(hi[i]); }
}

// ---- per-wave GEMM: 4 batch-tiles x 3 col-tiles, NK k-tiles (32 k each), 2-deep prefetch ----
template<int NK, typename TA>
__device__ __forceinline__ void gemm3(const TA* __restrict__ Ab, int ldA,
    const u16* __restrict__ W0, const u16* __restrict__ W1, const u16* __restrict__ W2,
    f32x4 (&acc)[4][3]) {
  bf16x8 af[2][4], wf[2][3];
  #pragma unroll
  for (int bt = 0; bt < 4; ++bt) loadA(af[0][bt], Ab + (size_t)bt*16*ldA);
  wf[0][0] = *(const bf16x8*)W0;
  wf[0][1] = *(const bf16x8*)W1;
  wf[0][2] = *(const bf16x8*)W2;
  #pragma unroll
  for (int kt = 0; kt < NK; ++kt) {
    const int cur = kt & 1, nxt = cur ^ 1;
    if (kt + 1 < NK) {
      const int ko = (kt + 1) * 32;
      #pragma unroll
      for (int bt = 0; bt < 4; ++bt) loadA(af[nxt][bt], Ab + (size_t)bt*16*ldA + ko);
      wf[nxt][0] = *(const bf16x8*)(W0 + ko);
      wf[nxt][1] = *(const bf16x8*)(W1 + ko);
      wf[nxt][2] = *(const bf16x8*)(W2 + ko);
    }
    #pragma unroll
    for (int bt = 0; bt < 4; ++bt) {
      acc[bt][0] = __builtin_amdgcn_mfma_f32_16x16x32_bf16(af[cur][bt], wf[cur][0], acc[bt][0], 0,0,0);
      acc[bt][1] = __builtin_amdgcn_mfma_f32_16x16x32_bf16(af[cur][bt], wf[cur][1], acc[bt][1], 0,0,0);
      acc[bt][2] = __builtin_amdgcn_mfma_f32_16x16x32_bf16(af[cur][bt], wf[cur][2], acc[bt][2], 0,0,0);
    }
  }
}

// ---- park (write) or accumulate (add) a wave's acc into LDS [64][LW] ----
template<int LW>
__device__ __forceinline__ void parkAcc(float* L, f32x4 (&acc)[4][3], int ct0, int l15, int l4, bool add) {
  #pragma unroll
  for (int bt = 0; bt < 4; ++bt)
    #pragma unroll
    for (int ci = 0; ci < 3; ++ci) {
      const int col = (ct0 + ci)*16 + l15;
      #pragma unroll
      for (int q = 0; q < 4; ++q) {
        float* s = L + (bt*16 + l4*4 + q)*LW + col;
        if (add) *s += acc[bt][ci][q]; else *s = acc[bt][ci][q];
      }
    }
}

// ---- fused global GRU (32 blocks x 256 thr, 32 cols each): GEMMs + combine ----
__device__ void fusedG(const DPar& p, int t, int bj, char* ldsraw) {
  float* LI = (float*)ldsraw;          // [64][96] i-part
  float* LH = LI + 64*96;              // [64][96] h-part
  const int tid = (int)threadIdx.x;
  const int wave = tid >> 6, kh = wave >> 1, cg = wave & 1;
  const int lane = tid & 63, l15 = lane & 15, l4 = lane >> 4;
  const int j0 = bj*32, ct0 = cg*3;
  f32x4 ai[4][3], ah[4][3];
  #pragma unroll
  for (int i = 0; i < 4; ++i)
    #pragma unroll
    for (int c = 0; c < 3; ++c) { ai[i][c] = (f32x4){0,0,0,0}; ah[i][c] = (f32x4){0,0,0,0}; }
  auto wrow = [&](int ci){ const int ct = ct0 + ci; return (ct>>1)*1024 + j0 + ((ct&1)<<4) + l15; };
  { // i-part: X = [feat_t | qsel_t], K=2048; kh=0 half = feat (fp32), kh=1 half = qselb (bf16)
    const int kofs = kh*1024 + l4*8;
    const u16* W0 = p.A1 + (size_t)wrow(0)*2048 + kofs;
    const u16* W1 = p.A1 + (size_t)wrow(1)*2048 + kofs;
    const u16* W2 = p.A1 + (size_t)wrow(2)*2048 + kofs;
    if (kh == 0) gemm3<32>(p.feat + (size_t)t*BB*DD + (size_t)l15*DD + l4*8, DD, W0, W1, W2, ai);
    else         gemm3<32>(p.qselb + (size_t)l15*DD + l4*8, DD, W0, W1, W2, ai);
  }
  if (t) { // h-part: g_{t-1}, K=1024 split in kh halves of 512
    const int kofs = kh*512 + l4*8;
    const u16* W0 = p.A2 + (size_t)wrow(0)*1024 + kofs;
    const u16* W1 = p.A2 + (size_t)wrow(1)*1024 + kofs;
    const u16* W2 = p.A2 + (size_t)wrow(2)*1024 + kofs;
    gemm3<16>(p.ghist + (size_t)(t-1)*BB*DD + (size_t)l15*DD + kh*512 + l4*8, DD, W0, W1, W2, ah);
  }
  if (kh == 1) { parkAcc<96>(LI, ai, ct0, l15, l4, false); parkAcc<96>(LH, ah, ct0, l15, l4, false); }
  __syncthreads();
  if (kh == 0) { parkAcc<96>(LI, ai, ct0, l15, l4, true);  parkAcc<96>(LH, ah, ct0, l15, l4, true); }
  __syncthreads();
  // pointwise: b = tid>>2 (0..63), jjb = (tid&3)*8
  const int b = tid >> 2, jjb = (tid & 3)*8;
  const float* Lib = LI + b*96;
  const float* Lhb = LH + b*96;
  float gv8[8]; float scp = 0.f;
  #pragma unroll
  for (int i = 0; i < 8; ++i) {
    const int jj = jjb + i, j = j0 + jj;
    const float r_ = sigm(Lib[jj]     + p.bihg[j]      + Lhb[jj]    + p.bhhg[j]);
    const float z_ = sigm(Lib[32+jj]  + p.bihg[1024+j] + Lhb[32+jj] + p.bhhg[1024+j]);
    const float n_ = tanh_(Lib[64+jj] + p.bihg[2048+j] + r_*(Lhb[64+jj] + p.bhhg[2048+j]));
    const float gp = p.gf[(size_t)b*DD + j];
    const float gv = (1.f - z_)*n_ + z_*gp;
    p.gf[(size_t)b*DD + j] = gv;
    gv8[i] = gv;
    scp += gv * p.watt[j];
  }
  bf16x8 hh;
  #pragma unroll
  for (int i = 0; i < 8; ++i) hh[i] = (short)f2b(gv8[i]);
  *(bf16x8*)(p.ghist + (size_t)t*BB*DD + (size_t)b*DD + j0 + jjb) = hh;
  scp += __shfl_xor(scp, 1); scp += __shfl_xor(scp, 2);
  if ((tid & 3) == 0) p.scoresP[(size_t)t*32*BB + (size_t)bj*BB + b] = scp;
}

// ---- fused emotion GRU (32 blocks x 256 thr): emotion step td = t-1 ----
__device__ void fusedE(const DPar& p, int t, int bj, char* ldsraw) {
  const int td = t - 1;
  float* LI = (float*)ldsraw;
  float* LH = LI + 64*96;
  const int tid = (int)threadIdx.x;
  const int wave = tid >> 6, kh = wave >> 1, cg = wave & 1;
  const int lane = tid & 63, l15 = lane & 15, l4 = lane >> 4;
  const int j0 = bj*32, ct0 = cg*3;
  f32x4 ai[4][3], ah[4][3];
  #pragma unroll
  for (int i = 0; i < 4; ++i)
    #pragma unroll
    for (int c = 0; c < 3; ++c) { ai[i][c] = (f32x4){0,0,0,0}; ah[i][c] = (f32x4){0,0,0,0}; }
  auto wrow = [&](int ci){ const int ct = ct0 + ci; return (ct>>1)*1024 + j0 + ((ct&1)<<4) + l15; };
  { // i-part: qnew_{td} (bf16), K=1024
    const int kofs = kh*512 + l4*8;
    const u16* W0 = p.A5 + (size_t)wrow(0)*1024 + kofs;
    const u16* W1 = p.A5 + (size_t)wrow(1)*1024 + kofs;
    const u16* W2 = p.A5 + (size_t)wrow(2)*1024 + kofs;
    gemm3<16>(p.qnewb + (size_t)l15*DD + kh*512 + l4*8, DD, W0, W1, W2, ai);
  }
  if (td > 0) { // h-part: e_{td-1} from ebuf[t&1]
    const u16* ebr = (t & 1) ? p.eb1 : p.eb0;
    const int kofs = kh*512 + l4*8;
    const u16* W0 = p.A6 + (size_t)wrow(0)*1024 + kofs;
    const u16* W1 = p.A6 + (size_t)wrow(1)*1024 + kofs;
    const u16* W2 = p.A6 + (size_t)wrow(2)*1024 + kofs;
    gemm3<16>(ebr + (size_t)l15*DD + kh*512 + l4*8, DD, W0, W1, W2, ah);
  }
  if (kh == 1) { parkAcc<96>(LI, ai, ct0, l15, l4, false); parkAcc<96>(LH, ah, ct0, l15, l4, false); }
  __syncthreads();
  if (kh == 0) { parkAcc<96>(LI, ai, ct0, l15, l4, true);  parkAcc<96>(LH, ah, ct0, l15, l4, true); }
  __syncthreads();
  const int b = tid >> 2, jjb = (tid & 3)*8;
  const float* Lib = LI + b*96;
  const float* Lhb = LH + b*96;
  float ev8[8];
  #pragma unroll
  for (int i = 0; i < 8; ++i) {
    const int jj = jjb + i, j = j0 + jj;
    const float r_ = sigm(Lib[jj]     + p.bihe[j]      + Lhb[jj]    + p.bhhe[j]);
    const float z_ = sigm(Lib[32+jj]  + p.bihe[1024+j] + Lhb[32+jj] + p.bhhe[1024+j]);
    const float n_ = tanh_(Lib[64+jj] + p.bihe[2048+j] + r_*(Lhb[64+jj] + p.bhhe[2048+j]));
    const float ep = p.ef[(size_t)b*DD + j];
    const float ev = (1.f - z_)*n_ + z_*ep;
    p.ef[(size_t)b*DD + j] = ev;
    ev8[i] = ev;
  }
  float* orow = p.out + (size_t)td*BB*DD + (size_t)b*DD + j0 + jjb;
  *(f32x4*)orow       = (f32x4){ev8[0], ev8[1], ev8[2], ev8[3]};
  *(f32x4*)(orow + 4) = (f32x4){ev8[4], ev8[5], ev8[6], ev8[7]};
  u16* ebw = ((t-1) & 1) ? p.eb1 : p.eb0;
  bf16x8 ee;
  #pragma unroll
  for (int i = 0; i < 8; ++i) ee[i] = (short)f2b(ev8[i]);
  *(bf16x8*)(ebw + (size_t)b*DD + j0 + jjb) = ee;
}

// ---- attention (64 blocks x 256 thr, one per batch): c_t from history < t ----
__device__ void attn_run(const DPar& p, int t, int b, float* smem) {
  float* al = smem;          // [128] alpha
  float* rs = smem + 128;    // [4] wave partials
  float* part = smem + 160;  // [4][64][16]
  const int tid = (int)threadIdx.x;
  float s = -1e30f;
  if (tid < t) {
    const float* sp = p.scoresP + (size_t)tid*(32*BB) + b;
    float a0 = 0.f;
    #pragma unroll
    for (int pp = 0; pp < 32; ++pp) a0 += sp[pp*BB];
    s = a0;
  }
  if (tid < 128) {
    float m = s;
    #pragma unroll
    for (int o = 1; o < 64; o <<= 1) m = fmaxf(m, __shfl_xor(m, o));
    if ((tid & 63) == 0) rs[tid >> 6] = m;
  }
  __syncthreads();
  const float m = fmaxf(rs[0], rs[1]);
  const float e = (tid < t) ? __expf(s - m) : 0.f;
  if (tid < 128) {
    float sum = e;
    #pragma unroll
    for (int o = 1; o < 64; o <<= 1) sum += __shfl_xor(sum, o);
    if ((tid & 63) == 0) rs[2 + (tid >> 6)] = sum;
  }
  __syncthreads();
  if (tid < 128) al[tid] = e / (rs[2] + rs[3]);
  __syncthreads();
  const int ug = tid >> 6, dg = tid & 63;
  float acc[16];
  #pragma unroll
  for (int i = 0; i < 16; ++i) acc[i] = 0.f;
  const u16* gb = p.ghist + (size_t)b*DD + dg*16;
  for (int u0 = ug; u0 < t; u0 += 32) {
    bf16x8 g0[8], g1[8]; float av[8];
    #pragma unroll
    for (int i = 0; i < 8; ++i) {
      const int u = u0 + i*4;
      if (u < t) {
        g0[i] = *(const bf16x8*)(gb + (size_t)u*BB*DD);
        g1[i] = *(const bf16x8*)(gb + (size_t)u*BB*DD + 8);
        av[i] = al[u];
      } else {
        av[i] = 0.f;
        g0[i] = (bf16x8){0,0,0,0,0,0,0,0};
        g1[i] = (bf16x8){0,0,0,0,0,0,0,0};
      }
    }
    #pragma unroll
    for (int i = 0; i < 8; ++i)
      #pragma unroll
      for (int d = 0; d < 8; ++d) {
        acc[d]   += av[i] * b2f((u16)g0[i][d]);
        acc[8+d] += av[i] * b2f((u16)g1[i][d]);
      }
  }
  #pragma unroll
  for (int i = 0; i < 4; ++i)
    *(f32x4*)(part + ((size_t)(ug*64 + dg))*16 + i*4) =
      (f32x4){acc[i*4], acc[i*4+1], acc[i*4+2], acc[i*4+3]};
  __syncthreads();
  const int d = tid * 4;
  const int dgf = d >> 4, di = d & 15;
  f32x4 sum = {0,0,0,0};
  #pragma unroll
  for (int u2 = 0; u2 < 4; ++u2) sum += *(f32x4*)(part + ((size_t)(u2*64 + dgf))*16 + di);
  s16x4 o;
  #pragma unroll
  for (int q = 0; q < 4; ++q) o[q] = (short)f2b(sum[q]);
  *(s16x4*)(p.cb + (size_t)b*DD + d) = o;
}

// ---- round-7-proven 64x64-tile GEMM, 256 thr (2 K-halves x 2 N-halves) ----
template<typename TA>
__device__ __attribute__((noinline)) void gemm_frag(
    const TA* __restrict__ A, const u16* __restrict__ W, int ldW,
    int k0, int n0, float* __restrict__ C, float* red) {
  const int tid = threadIdx.x;
  const int wv  = tid >> 6;
  const int kh  = wv >> 1;
  const int nh  = wv & 1;
  const int lane = tid & 63;
  const int l15 = lane & 15;
  const int l4  = lane >> 4;
  const TA*  Ab = A + (size_t)l15 * DD + kh * 512 + l4 * 8;
  const u16* Wb = W + (size_t)(n0 + nh*32 + l15) * ldW + k0 + kh * 512 + l4 * 8;

  f32x4 acc[4][2];
  #pragma unroll
  for (int i = 0; i < 4; ++i) { acc[i][0] = (f32x4){0,0,0,0}; acc[i][1] = (f32x4){0,0,0,0}; }

  bf16x8 af[2][4], wf[2][2];
  #pragma unroll
  for (int bt = 0; bt < 4; ++bt) loadA(af[0][bt], Ab + (size_t)bt*16*DD);
  wf[0][0] = *(const bf16x8*)(Wb);
  wf[0][1] = *(const bf16x8*)(Wb + (size_t)16*ldW);

  #pragma unroll
  for (int kt = 0; kt < 16; ++kt) {
    const int cur = kt & 1, nxt = cur ^ 1;
    if (kt < 15) {
      const int ko = (kt + 1) * 32;
      #pragma unroll
      for (int bt = 0; bt < 4; ++bt) loadA(af[nxt][bt], Ab + (size_t)bt*16*DD + ko);
      wf[nxt][0] = *(const bf16x8*)(Wb + ko);
      wf[nxt][1] = *(const bf16x8*)(Wb + (size_t)16*ldW + ko);
    }
    #pragma unroll
    for (int bt = 0; bt < 4; ++bt) {
      acc[bt][0] = __builtin_amdgcn_mfma_f32_16x16x32_bf16(af[cur][bt], wf[cur][0], acc[bt][0], 0,0,0);
      acc[bt][1] = __builtin_amdgcn_mfma_f32_16x16x32_bf16(af[cur][bt], wf[cur][1], acc[bt][1], 0,0,0);
    }
  }
  if (kh == 1) {
    #pragma unroll
    for (int bt = 0; bt < 4; ++bt)
      #pragma unroll
      for (int nt = 0; nt < 2; ++nt)
        #pragma unroll
        for (int q = 0; q < 4; ++q)
          red[(bt*16 + l4*4 + q)*64 + nh*32 + nt*16 + l15] = acc[bt][nt][q];
  }
  __syncthreads();
  if (kh == 0) {
    #pragma unroll
    for (int bt = 0; bt < 4; ++bt)
      #pragma unroll
      for (int nt = 0; nt < 2; ++nt)
        #pragma unroll
        for (int q = 0; q < 4; ++q) {
          const int row = bt*16 + l4*4 + q;
          const int col = nh*32 + nt*16 + l15;
          C[(size_t)row*G3 + n0 + col] = acc[bt][nt][q] + red[row*64 + col];
        }
  }
}

// ---- K1: GIPa(48) | GHP(48) | fusedG(32) | fusedE(32) | attn(64) = 224 blocks x 256 ----
__global__ void __launch_bounds__(256) k1_step(DPar p, int t) {
  __shared__ __align__(16) char lds[49152];
  const int blk = (int)blockIdx.x;
  if (blk < 48)        gemm_frag(p.feat + (size_t)t*BB*DD, p.A3, 2048, 0, blk*64, p.GIPa, (float*)lds);
  else if (blk < 96)   gemm_frag(p.qselb, p.A4, 1024, 0, (blk-48)*64, p.GHP, (float*)lds);
  else if (blk < 128)  fusedG(p, t, blk-96, lds);
  else if (blk < 160)  { if (t) fusedE(p, t, blk-128, lds); }
  else                 { if (t) attn_run(p, t, blk-160, (float*)lds); }
}

// ---- K2: fused party GRU (32 blocks x 256): GIPb slice + combineQ ----
__global__ void __launch_bounds__(256) k2_step(DPar p, int t) {
  __shared__ __align__(16) float LI[64*96];
  const int tid = (int)threadIdx.x;
  const int bj  = (int)blockIdx.x;      // 0..31
  const int wave = tid >> 6, kh = wave >> 1, cg = wave & 1;
  const int lane = tid & 63, l15 = lane & 15, l4 = lane >> 4;
  const int j0 = bj*32, ct0 = cg*3;
  f32x4 ai[4][3];
  #pragma unroll
  for (int i = 0; i < 4; ++i)
    #pragma unroll
    for (int c = 0; c < 3; ++c) ai[i][c] = (f32x4){0,0,0,0};
  {
    auto wrow = [&](int ci){ const int ct = ct0 + ci; return (ct>>1)*1024 + j0 + ((ct&1)<<4) + l15; };
    const int kofs = 1024 + kh*512 + l4*8;
    const u16* W0 = p.A3 + (size_t)wrow(0)*2048 + kofs;
    const u16* W1 = p.A3 + (size_t)wrow(1)*2048 + kofs;
    const u16* W2 = p.A3 + (size_t)wrow(2)*2048 + kofs;
    gemm3<16>(p.cb + (size_t)l15*DD + kh*512 + l4*8, DD, W0, W1, W2, ai);
  }
  if (kh == 1) parkAcc<96>(LI, ai, ct0, l15, l4, false);
  __syncthreads();
  if (kh == 0) parkAcc<96>(LI, ai, ct0, l15, l4, true);
  __syncthreads();
  const int b = tid >> 2, jjb = (tid & 3)*8;
  const int spkc = p.spk[t*BB + b];
  const int spkn = (t+1 < TT) ? p.spk[(t+1)*BB + b] : spkc;
  float* prow = p.parties + (size_t)(b*2 + spkc)*DD;
  const float* orow = p.parties + (size_t)(b*2 + spkn)*DD;
  const float* Gia = p.GIPa + (size_t)b*G3;
  const float* Ghp = p.GHP  + (size_t)b*G3;
  const float* Lib = LI + b*96;
  float qn8[8], qs8[8];
  #pragma unroll
  for (int i = 0; i < 8; ++i) {
    const int jj = jjb + i, j = j0 + jj;
    const float gi_r = Gia[j]      + Lib[jj]    + p.bihp[j];
    const float gi_z = Gia[1024+j] + Lib[32+jj] + p.bihp[1024+j];
    const float gi_n = Gia[2048+j] + Lib[64+jj] + p.bihp[2048+j];
    const float gh_r = Ghp[j]      + p.bhhp[j];
    const float gh_z = Ghp[1024+j] + p.bhhp[1024+j];
    const float gh_n = Ghp[2048+j] + p.bhhp[2048+j];
    const float r_ = sigm(gi_r + gh_r);
    const float z_ = sigm(gi_z + gh_z);
    const float n_ = tanh_(gi_n + r_*gh_n);
    const float h  = prow[j];
    const float qv = (1.f - z_)*n_ + z_*h;
    prow[j] = qv;
    qn8[i] = qv;
    qs8[i] = (spkn == spkc) ? qv : orow[j];
  }
  bf16x8 qn, qs;
  #pragma unroll
  for (int i = 0; i < 8; ++i) { qn[i] = (short)f2b(qn8[i]); qs[i] = (short)f2b(qs8[i]); }
  *(bf16x8*)(p.qnewb + (size_t)b*DD + j0 + jjb) = qn;
  *(bf16x8*)(p.qselb + (size_t)b*DD + j0 + jjb) = qs;
}

// ---- epilogue: emotion step 127 ----
__global__ void __launch_bounds__(256) kE_epi(DPar p) {
  __shared__ __align__(16) char lds[49152];
  fusedE(p, TT, (int)blockIdx.x, lds);
}

// ---- weight fp32 -> bf16 cast ----
__global__ void convertK(const float* __restrict__ Wg, const float* __restrict__ Whg,
                         const float* __restrict__ Wp, const float* __restrict__ Whp,
                         const float* __restrict__ We, const float* __restrict__ Whe,
                         u16* A1, u16* A2, u16* A3, u16* A4, u16* A5, u16* A6) {
  const long n1 = (long)G3*2048/4, n2 = (long)G3*1024/4;
  const long tot = 2*n1 + 4*n2;
  long gid = (long)blockIdx.x*256 + threadIdx.x;
  const long stride = (long)gridDim.x*256;
  for (long i = gid; i < tot; i += stride) {
    const float* src; u16* dst; long o = i;
    if (o < n1) { src = Wg;  dst = A1; }
    else { o -= n1;
      if (o < n2) { src = Whg; dst = A2; }
      else { o -= n2;
        if (o < n1) { src = Wp; dst = A3; }
        else { o -= n1;
          if (o < n2) { src = Whp; dst = A4; }
          else { o -= n2;
            if (o < n2) { src = We; dst = A5; }
            else { o -= n2; src = Whe; dst = A6; }
          }
        }
      }
    }
    f32x4 v = *(const f32x4*)(src + o*4);
    s16x4 w;
    w[0] = (short)f2b(v[0]); w[1] = (short)f2b(v[1]);
    w[2] = (short)f2b(v[2]); w[3] = (short)f2b(v[3]);
    *(s16x4*)(dst + o*4) = w;
  }
}

// ---- zero state + speaker idx (runs every launch; replay/poison-safe) ----
__global__ void initK(float* parties, float* gf, float* ef,
                      u16* cb, u16* qselb, u16* qnewb, u16* eb0, u16* eb1,
                      const float* spkOH, int* spk) {
  const int i = blockIdx.x*256 + threadIdx.x;
  if (i < BB*2*DD) parties[i] = 0.f;
  if (i < BB*DD) {
    gf[i] = 0.f; ef[i] = 0.f;
    cb[i] = 0; qselb[i] = 0; qnewb[i] = 0; eb0[i] = 0; eb1[i] = 0;
  }
  if (i < TT*BB) spk[i] = (spkOH[(size_t)i*2 + 1] > 0.5f) ? 1 : 0;
}

extern "C" void kernel_launch(void* const* d_in, const int* in_sizes, int n_in,
                              void* d_out, int out_size, void* d_ws, size_t ws_size,
                              hipStream_t stream) {
  const float* feat  = (const float*)d_in[0];
  const float* spkOH = (const float*)d_in[1];
  const float* Wih_g = (const float*)d_in[2];
  const float* Whh_g = (const float*)d_in[3];
  const float* bih_g = (const float*)d_in[4];
  const float* bhh_g = (const float*)d_in[5];
  const float* Wih_p = (const float*)d_in[6];
  const float* Whh_p = (const float*)d_in[7];
  const float* bih_p = (const float*)d_in[8];
  const float* bhh_p = (const float*)d_in[9];
  const float* Wih_e = (const float*)d_in[10];
  const float* Whh_e = (const float*)d_in[11];
  const float* bih_e = (const float*)d_in[12];
  const float* bhh_e = (const float*)d_in[13];
  const float* watt  = (const float*)d_in[14];

  char* w = (char*)d_ws;
  auto alloc = [&](size_t bytes) -> char* {
    char* r = w; w += (bytes + 255) & ~(size_t)255; return r;
  };
  u16* ghist = (u16*)alloc((size_t)TT*BB*DD*2);
  float* scoresP = (float*)alloc((size_t)TT*32*BB*4);
  u16* cb    = (u16*)alloc((size_t)BB*DD*2);
  u16* qselb = (u16*)alloc((size_t)BB*DD*2);
  u16* qnewb = (u16*)alloc((size_t)BB*DD*2);
  u16* eb0   = (u16*)alloc((size_t)BB*DD*2);
  u16* eb1   = (u16*)alloc((size_t)BB*DD*2);
  float* parties = (float*)alloc((size_t)BB*2*DD*4);
  float* gf  = (float*)alloc((size_t)BB*DD*4);
  float* ef  = (float*)alloc((size_t)BB*DD*4);
  float* GIPa = (float*)alloc((size_t)BB*G3*4);
  float* GHP  = (float*)alloc((size_t)BB*G3*4);
  int* spk    = (int*)alloc((size_t)TT*BB*4);
  u16* A1 = (u16*)alloc((size_t)G3*2048*2);
  u16* A2 = (u16*)alloc((size_t)G3*1024*2);
  u16* A3 = (u16*)alloc((size_t)G3*2048*2);
  u16* A4 = (u16*)alloc((size_t)G3*1024*2);
  u16* A5 = (u16*)alloc((size_t)G3*1024*2);
  u16* A6 = (u16*)alloc((size_t)G3*1024*2);
  const size_t need = (size_t)(w - (char*)d_ws);   // ~59 MB, well under proven 75.5 MB bound
  if (ws_size < need) return;   // fail validation visibly rather than fault

  hipLaunchKernelGGL(convertK, dim3(2048), dim3(256), 0, stream,
                     Wih_g, Whh_g, Wih_p, Whh_p, Wih_e, Whh_e,
                     A1, A2, A3, A4, A5, A6);
  hipLaunchKernelGGL(initK, dim3(512), dim3(256), 0, stream,
                     parties, gf, ef, cb, qselb, qnewb, eb0, eb1, spkOH, spk);

  DPar p;
  p.A1 = A1; p.A2 = A2; p.A3 = A3; p.A4 = A4; p.A5 = A5; p.A6 = A6;
  p.feat = feat;
  p.ghist = ghist; p.cb = cb; p.qselb = qselb; p.qnewb = qnewb; p.eb0 = eb0; p.eb1 = eb1;
  p.scoresP = scoresP; p.parties = parties; p.gf = gf; p.ef = ef;
  p.GIPa = GIPa; p.GHP = GHP;
  p.bihg = bih_g; p.bhhg = bhh_g; p.bihp = bih_p; p.bhhp = bhh_p;
  p.bihe = bih_e; p.bhhe = bhh_e; p.watt = watt;
  p.spk = spk; p.out = (float*)d_out;

  for (int t = 0; t < TT; ++t) {
    hipLaunchKernelGGL(k1_step, dim3(224), dim3(256), 0, stream, p, t);
    hipLaunchKernelGGL(k2_step, dim3(32),  dim3(256), 0, stream, p, t);
  }
  hipLaunchKernelGGL(kE_epi, dim3(32), dim3(256), 0, stream, p);
}

// Round 10
// 10156.309 us; speedup vs baseline: 1.1710x; 1.1710x over previous
//
#include <hip/hip_runtime.h>
#include <stdint.h>

#define TT 128
#define BB 64
#define DD 1024
#define G3 3072

typedef unsigned short u16;
typedef unsigned int u32;
typedef __attribute__((ext_vector_type(8))) short bf16x8;
typedef __attribute__((ext_vector_type(4))) short s16x4;
typedef __attribute__((ext_vector_type(4))) float f32x4;

__device__ __forceinline__ float b2f(u16 h){ u32 u = ((u32)h)<<16; float f; __builtin_memcpy(&f,&u,4); return f; }
__device__ __forceinline__ u16 f2b(float f){ u32 u; __builtin_memcpy(&u,&f,4); u = (u + 0x7fffu + ((u>>16)&1u))>>16; return (u16)u; }
__device__ __forceinline__ float sigm(float x){ return 1.f/(1.f+__expf(-x)); }
__device__ __forceinline__ float tanh_(float x){
  if (x > 10.f) return 1.f;
  if (x < -10.f) return -1.f;
  float e = __expf(2.f*x); return (e-1.f)/(e+1.f);
}

struct DPar {
  const u16 *A1,*A2,*A3,*A4,*A5,*A6;   // bf16 weights
  const float* feat;
  u16 *ghist,*cb,*qselb,*qnewb,*eb0,*eb1;
  float *scoresP;                       // [TT][64][BB] per-block score partials
  float *parties,*gf,*ef,*GIPa0,*GIPa1,*GHP;
  const float *bihg,*bhhg,*bihp,*bhhp,*bihe,*bhhe,*watt;
  const int* spk;
  float* out;
};

// ---- A-fragment loaders (bf16 direct; fp32 converted in-flight) ----
__device__ __forceinline__ void loadA(bf16x8& d, const u16* p){ d = *(const bf16x8*)p; }
__device__ __forceinline__ void loadA(bf16x8& d, const float* p){
  f32x4 lo = *(const f32x4*)p;
  f32x4 hi = *(const f32x4*)(p + 4);
  #pragma unroll
  for (int i = 0; i < 4; ++i) { d[i] = (short)f2b(lo[i]); d[i+4] = (short)f2b(hi[i]); }
}

// ---- per-wave GEMM: 4 batch-tiles x 3 gate-tiles, NK k-tiles (32 k each), 2-deep prefetch ----
template<int NK, typename TA>
__device__ __forceinline__ void gemm3(const TA* __restrict__ Ab, int ldA,
    const u16* __restrict__ W0, const u16* __restrict__ W1, const u16* __restrict__ W2,
    f32x4 (&acc)[4][3]) {
  bf16x8 af[2][4], wf[2][3];
  #pragma unroll
  for (int bt = 0; bt < 4; ++bt) loadA(af[0][bt], Ab + (size_t)bt*16*ldA);
  wf[0][0] = *(const bf16x8*)W0;
  wf[0][1] = *(const bf16x8*)W1;
  wf[0][2] = *(const bf16x8*)W2;
  #pragma unroll
  for (int kt = 0; kt < NK; ++kt) {
    const int cur = kt & 1, nxt = cur ^ 1;
    if (kt + 1 < NK) {
      const int ko = (kt + 1) * 32;
      #pragma unroll
      for (int bt = 0; bt < 4; ++bt) loadA(af[nxt][bt], Ab + (size_t)bt*16*ldA + ko);
      wf[nxt][0] = *(const bf16x8*)(W0 + ko);
      wf[nxt][1] = *(const bf16x8*)(W1 + ko);
      wf[nxt][2] = *(const bf16x8*)(W2 + ko);
    }
    #pragma unroll
    for (int bt = 0; bt < 4; ++bt) {
      acc[bt][0] = __builtin_amdgcn_mfma_f32_16x16x32_bf16(af[cur][bt], wf[cur][0], acc[bt][0], 0,0,0);
      acc[bt][1] = __builtin_amdgcn_mfma_f32_16x16x32_bf16(af[cur][bt], wf[cur][1], acc[bt][1], 0,0,0);
      acc[bt][2] = __builtin_amdgcn_mfma_f32_16x16x32_bf16(af[cur][bt], wf[cur][2], acc[bt][2], 0,0,0);
    }
  }
}

// ---- park (write) or accumulate (add) a wave's acc into LDS [64][48] ----
__device__ __forceinline__ void parkAcc48(float* L, f32x4 (&acc)[4][3], int l15, int l4, bool add) {
  #pragma unroll
  for (int bt = 0; bt < 4; ++bt)
    #pragma unroll
    for (int ci = 0; ci < 3; ++ci) {
      const int col = ci*16 + l15;
      #pragma unroll
      for (int q = 0; q < 4; ++q) {
        float* s = L + (bt*16 + l4*4 + q)*48 + col;
        if (add) *s += acc[bt][ci][q]; else *s = acc[bt][ci][q];
      }
    }
}

// ---- fused global GRU (64 blocks x 256 thr, 16 cols): 4-way-K GEMMs + combine ----
__device__ void fusedG(const DPar& p, int t, int bj, char* ldsraw) {
  float* LI0 = (float*)ldsraw;     // each region [64][48] f32 = 12 KB
  float* LI1 = LI0 + 3072;
  float* LH0 = LI1 + 3072;
  float* LH1 = LH0 + 3072;
  const int tid = (int)threadIdx.x;
  const int kq = tid >> 6;
  const int lane = tid & 63, l15 = lane & 15, l4 = lane >> 4;
  const int lofs = l4 * 8;
  const int j0 = bj * 16;
  const size_t r0 = (size_t)(j0 + l15);
  f32x4 ai[4][3], ah[4][3];
  #pragma unroll
  for (int i = 0; i < 4; ++i)
    #pragma unroll
    for (int c = 0; c < 3; ++c) { ai[i][c] = (f32x4){0,0,0,0}; ah[i][c] = (f32x4){0,0,0,0}; }
  { // i-part: X = [feat | qsel], K=2048; quarters: kq0,1 = feat halves, kq2,3 = qsel halves
    const int kw = (kq < 2) ? kq*512 : 1024 + (kq - 2)*512;
    const u16* W0 = p.A1 + (r0       )*2048 + kw + lofs;
    const u16* W1 = p.A1 + (r0 + 1024)*2048 + kw + lofs;
    const u16* W2 = p.A1 + (r0 + 2048)*2048 + kw + lofs;
    if (kq < 2) gemm3<16>(p.feat + (size_t)t*BB*DD + (size_t)l15*DD + kq*512 + lofs, DD, W0, W1, W2, ai);
    else        gemm3<16>(p.qselb + (size_t)l15*DD + (kq-2)*512 + lofs, DD, W0, W1, W2, ai);
  }
  if (t) { // h-part: g_{t-1}, K=1024 quarters of 256
    const int kw = kq*256;
    const u16* W0 = p.A2 + (r0       )*1024 + kw + lofs;
    const u16* W1 = p.A2 + (r0 + 1024)*1024 + kw + lofs;
    const u16* W2 = p.A2 + (r0 + 2048)*1024 + kw + lofs;
    gemm3<8>(p.ghist + (size_t)(t-1)*BB*DD + (size_t)l15*DD + kw + lofs, DD, W0, W1, W2, ah);
  }
  if (kq == 1) { parkAcc48(LI0, ai, l15, l4, false); parkAcc48(LH0, ah, l15, l4, false); }
  if (kq == 3) { parkAcc48(LI1, ai, l15, l4, false); parkAcc48(LH1, ah, l15, l4, false); }
  __syncthreads();
  if (kq == 0) { parkAcc48(LI0, ai, l15, l4, true); parkAcc48(LH0, ah, l15, l4, true); }
  if (kq == 2) { parkAcc48(LI1, ai, l15, l4, true); parkAcc48(LH1, ah, l15, l4, true); }
  __syncthreads();
  if (tid < 128) {
    const int b = tid >> 1, jjb = (tid & 1) * 8;
    const float* i0 = LI0 + b*48; const float* i1 = LI1 + b*48;
    const float* h0 = LH0 + b*48; const float* h1 = LH1 + b*48;
    float gv8[8]; float scp = 0.f;
    #pragma unroll
    for (int i = 0; i < 8; ++i) {
      const int jj = jjb + i, j = j0 + jj;
      const float ir = i0[jj]    + i1[jj]    + p.bihg[j];
      const float iz = i0[16+jj] + i1[16+jj] + p.bihg[1024+j];
      const float in_= i0[32+jj] + i1[32+jj] + p.bihg[2048+j];
      const float hr = h0[jj]    + h1[jj]    + p.bhhg[j];
      const float hz = h0[16+jj] + h1[16+jj] + p.bhhg[1024+j];
      const float hn = h0[32+jj] + h1[32+jj] + p.bhhg[2048+j];
      const float r_ = sigm(ir + hr);
      const float z_ = sigm(iz + hz);
      const float n_ = tanh_(in_ + r_*hn);
      const float gp = p.gf[(size_t)b*DD + j];
      const float gv = (1.f - z_)*n_ + z_*gp;
      p.gf[(size_t)b*DD + j] = gv;
      gv8[i] = gv;
      scp += gv * p.watt[j];
    }
    bf16x8 hh;
    #pragma unroll
    for (int i = 0; i < 8; ++i) hh[i] = (short)f2b(gv8[i]);
    *(bf16x8*)(p.ghist + (size_t)t*BB*DD + (size_t)b*DD + j0 + jjb) = hh;
    scp += __shfl_xor(scp, 1);
    if ((tid & 1) == 0) p.scoresP[(size_t)t*64*BB + (size_t)bj*BB + b] = scp;
  }
}

// ---- fused emotion GRU (64 blocks x 256 thr, 16 cols): emotion step td = t-1 ----
__device__ void fusedE(const DPar& p, int t, int bj, char* ldsraw) {
  const int td = t - 1;
  float* LI0 = (float*)ldsraw;
  float* LI1 = LI0 + 3072;
  float* LH0 = LI1 + 3072;
  float* LH1 = LH0 + 3072;
  const int tid = (int)threadIdx.x;
  const int kq = tid >> 6;
  const int lane = tid & 63, l15 = lane & 15, l4 = lane >> 4;
  const int lofs = l4 * 8;
  const int j0 = bj * 16;
  const size_t r0 = (size_t)(j0 + l15);
  f32x4 ai[4][3], ah[4][3];
  #pragma unroll
  for (int i = 0; i < 4; ++i)
    #pragma unroll
    for (int c = 0; c < 3; ++c) { ai[i][c] = (f32x4){0,0,0,0}; ah[i][c] = (f32x4){0,0,0,0}; }
  { // i-part: qnew_{td}, K=1024 quarters
    const int kw = kq*256;
    const u16* W0 = p.A5 + (r0       )*1024 + kw + lofs;
    const u16* W1 = p.A5 + (r0 + 1024)*1024 + kw + lofs;
    const u16* W2 = p.A5 + (r0 + 2048)*1024 + kw + lofs;
    gemm3<8>(p.qnewb + (size_t)l15*DD + kw + lofs, DD, W0, W1, W2, ai);
  }
  if (td > 0) { // h-part: e_{td-1}
    const u16* ebr = (t & 1) ? p.eb1 : p.eb0;
    const int kw = kq*256;
    const u16* W0 = p.A6 + (r0       )*1024 + kw + lofs;
    const u16* W1 = p.A6 + (r0 + 1024)*1024 + kw + lofs;
    const u16* W2 = p.A6 + (r0 + 2048)*1024 + kw + lofs;
    gemm3<8>(ebr + (size_t)l15*DD + kw + lofs, DD, W0, W1, W2, ah);
  }
  if (kq == 1) { parkAcc48(LI0, ai, l15, l4, false); parkAcc48(LH0, ah, l15, l4, false); }
  if (kq == 3) { parkAcc48(LI1, ai, l15, l4, false); parkAcc48(LH1, ah, l15, l4, false); }
  __syncthreads();
  if (kq == 0) { parkAcc48(LI0, ai, l15, l4, true); parkAcc48(LH0, ah, l15, l4, true); }
  if (kq == 2) { parkAcc48(LI1, ai, l15, l4, true); parkAcc48(LH1, ah, l15, l4, true); }
  __syncthreads();
  if (tid < 128) {
    const int b = tid >> 1, jjb = (tid & 1) * 8;
    const float* i0 = LI0 + b*48; const float* i1 = LI1 + b*48;
    const float* h0 = LH0 + b*48; const float* h1 = LH1 + b*48;
    float ev8[8];
    #pragma unroll
    for (int i = 0; i < 8; ++i) {
      const int jj = jjb + i, j = j0 + jj;
      const float ir = i0[jj]    + i1[jj]    + p.bihe[j];
      const float iz = i0[16+jj] + i1[16+jj] + p.bihe[1024+j];
      const float in_= i0[32+jj] + i1[32+jj] + p.bihe[2048+j];
      const float hr = h0[jj]    + h1[jj]    + p.bhhe[j];
      const float hz = h0[16+jj] + h1[16+jj] + p.bhhe[1024+j];
      const float hn = h0[32+jj] + h1[32+jj] + p.bhhe[2048+j];
      const float r_ = sigm(ir + hr);
      const float z_ = sigm(iz + hz);
      const float n_ = tanh_(in_ + r_*hn);
      const float ep = p.ef[(size_t)b*DD + j];
      const float ev = (1.f - z_)*n_ + z_*ep;
      p.ef[(size_t)b*DD + j] = ev;
      ev8[i] = ev;
    }
    float* orow = p.out + (size_t)td*BB*DD + (size_t)b*DD + j0 + jjb;
    *(f32x4*)orow       = (f32x4){ev8[0], ev8[1], ev8[2], ev8[3]};
    *(f32x4*)(orow + 4) = (f32x4){ev8[4], ev8[5], ev8[6], ev8[7]};
    u16* ebw = ((t-1) & 1) ? p.eb1 : p.eb0;
    bf16x8 ee;
    #pragma unroll
    for (int i = 0; i < 8; ++i) ee[i] = (short)f2b(ev8[i]);
    *(bf16x8*)(ebw + (size_t)b*DD + j0 + jjb) = ee;
  }
}

// ---- attention (64 blocks x 256 thr, one per batch): c_t from history < t ----
__device__ void attn_run(const DPar& p, int t, int b, float* smem) {
  float* al = smem;          // [128] alpha
  float* rs = smem + 128;    // [4] wave partials
  float* part = smem + 160;  // [4][64][16]
  const int tid = (int)threadIdx.x;
  float s = -1e30f;
  if (tid < t) {
    const float* sp = p.scoresP + (size_t)tid*(64*BB) + b;
    float a0 = 0.f;
    #pragma unroll
    for (int pp = 0; pp < 64; ++pp) a0 += sp[pp*BB];
    s = a0;
  }
  if (tid < 128) {
    float m = s;
    #pragma unroll
    for (int o = 1; o < 64; o <<= 1) m = fmaxf(m, __shfl_xor(m, o));
    if ((tid & 63) == 0) rs[tid >> 6] = m;
  }
  __syncthreads();
  const float m = fmaxf(rs[0], rs[1]);
  const float e = (tid < t) ? __expf(s - m) : 0.f;
  if (tid < 128) {
    float sum = e;
    #pragma unroll
    for (int o = 1; o < 64; o <<= 1) sum += __shfl_xor(sum, o);
    if ((tid & 63) == 0) rs[2 + (tid >> 6)] = sum;
  }
  __syncthreads();
  if (tid < 128) al[tid] = e / (rs[2] + rs[3]);
  __syncthreads();
  const int ug = tid >> 6, dg = tid & 63;
  float acc[16];
  #pragma unroll
  for (int i = 0; i < 16; ++i) acc[i] = 0.f;
  const u16* gb = p.ghist + (size_t)b*DD + dg*16;
  for (int u0 = ug; u0 < t; u0 += 32) {
    bf16x8 g0[8], g1[8]; float av[8];
    #pragma unroll
    for (int i = 0; i < 8; ++i) {
      const int u = u0 + i*4;
      if (u < t) {
        g0[i] = *(const bf16x8*)(gb + (size_t)u*BB*DD);
        g1[i] = *(const bf16x8*)(gb + (size_t)u*BB*DD + 8);
        av[i] = al[u];
      } else {
        av[i] = 0.f;
        g0[i] = (bf16x8){0,0,0,0,0,0,0,0};
        g1[i] = (bf16x8){0,0,0,0,0,0,0,0};
      }
    }
    #pragma unroll
    for (int i = 0; i < 8; ++i)
      #pragma unroll
      for (int d = 0; d < 8; ++d) {
        acc[d]   += av[i] * b2f((u16)g0[i][d]);
        acc[8+d] += av[i] * b2f((u16)g1[i][d]);
      }
  }
  #pragma unroll
  for (int i = 0; i < 4; ++i)
    *(f32x4*)(part + ((size_t)(ug*64 + dg))*16 + i*4) =
      (f32x4){acc[i*4], acc[i*4+1], acc[i*4+2], acc[i*4+3]};
  __syncthreads();
  const int d = tid * 4;
  const int dgf = d >> 4, di = d & 15;
  f32x4 sum = {0,0,0,0};
  #pragma unroll
  for (int u2 = 0; u2 < 4; ++u2) sum += *(f32x4*)(part + ((size_t)(u2*64 + dgf))*16 + di);
  s16x4 o;
  #pragma unroll
  for (int q = 0; q < 4; ++q) o[q] = (short)f2b(sum[q]);
  *(s16x4*)(p.cb + (size_t)b*DD + d) = o;
}

// ---- proven 64x64-tile GEMM, 256 thr (2 K-halves x 2 N-halves), for GHP / GIPa ----
template<typename TA>
__device__ __attribute__((noinline)) void gemm_frag(
    const TA* __restrict__ A, const u16* __restrict__ W, int ldW,
    int k0, int n0, float* __restrict__ C, float* red) {
  const int tid = threadIdx.x;
  const int wv  = tid >> 6;
  const int kh  = wv >> 1;
  const int nh  = wv & 1;
  const int lane = tid & 63;
  const int l15 = lane & 15;
  const int l4  = lane >> 4;
  const TA*  Ab = A + (size_t)l15 * DD + kh * 512 + l4 * 8;
  const u16* Wb = W + (size_t)(n0 + nh*32 + l15) * ldW + k0 + kh * 512 + l4 * 8;

  f32x4 acc[4][2];
  #pragma unroll
  for (int i = 0; i < 4; ++i) { acc[i][0] = (f32x4){0,0,0,0}; acc[i][1] = (f32x4){0,0,0,0}; }

  bf16x8 af[2][4], wf[2][2];
  #pragma unroll
  for (int bt = 0; bt < 4; ++bt) loadA(af[0][bt], Ab + (size_t)bt*16*DD);
  wf[0][0] = *(const bf16x8*)(Wb);
  wf[0][1] = *(const bf16x8*)(Wb + (size_t)16*ldW);

  #pragma unroll
  for (int kt = 0; kt < 16; ++kt) {
    const int cur = kt & 1, nxt = cur ^ 1;
    if (kt < 15) {
      const int ko = (kt + 1) * 32;
      #pragma unroll
      for (int bt = 0; bt < 4; ++bt) loadA(af[nxt][bt], Ab + (size_t)bt*16*DD + ko);
      wf[nxt][0] = *(const bf16x8*)(Wb + ko);
      wf[nxt][1] = *(const bf16x8*)(Wb + (size_t)16*ldW + ko);
    }
    #pragma unroll
    for (int bt = 0; bt < 4; ++bt) {
      acc[bt][0] = __builtin_amdgcn_mfma_f32_16x16x32_bf16(af[cur][bt], wf[cur][0], acc[bt][0], 0,0,0);
      acc[bt][1] = __builtin_amdgcn_mfma_f32_16x16x32_bf16(af[cur][bt], wf[cur][1], acc[bt][1], 0,0,0);
    }
  }
  if (kh == 1) {
    #pragma unroll
    for (int bt = 0; bt < 4; ++bt)
      #pragma unroll
      for (int nt = 0; nt < 2; ++nt)
        #pragma unroll
        for (int q = 0; q < 4; ++q)
          red[(bt*16 + l4*4 + q)*64 + nh*32 + nt*16 + l15] = acc[bt][nt][q];
  }
  __syncthreads();
  if (kh == 0) {
    #pragma unroll
    for (int bt = 0; bt < 4; ++bt)
      #pragma unroll
      for (int nt = 0; nt < 2; ++nt)
        #pragma unroll
        for (int q = 0; q < 4; ++q) {
          const int row = bt*16 + l4*4 + q;
          const int col = nh*32 + nt*16 + l15;
          C[(size_t)row*G3 + n0 + col] = acc[bt][nt][q] + red[row*64 + col];
        }
  }
}

// ---- DA: fusedG(64) | fusedE(64) | attn(64) | GHP(48) = 240 blocks x 256 ----
__global__ void __launch_bounds__(256) k1_step(DPar p, int t) {
  __shared__ __align__(16) char lds[49152];
  const int blk = (int)blockIdx.x;
  if (blk < 64)        fusedG(p, t, blk, lds);
  else if (blk < 128)  { if (t) fusedE(p, t, blk-64, lds); }
  else if (blk < 192)  { if (t) attn_run(p, t, blk-128, (float*)lds); }
  else                 gemm_frag(p.qselb, p.A4, 1024, 0, (blk-192)*64, p.GHP, (float*)lds);
}

// ---- DB: party(64, 16 cols, 4-way K) + GIPa(t+1) (48) = 112 blocks x 256 ----
__global__ void __launch_bounds__(256) k2_step(DPar p, int t) {
  __shared__ __align__(16) float L[6144];   // 24 KB
  const int tid = (int)threadIdx.x;
  const int blk = (int)blockIdx.x;
  if (blk < 64) {
    float* LI0 = L;
    float* LI1 = L + 3072;
    const int kq = tid >> 6;
    const int lane = tid & 63, l15 = lane & 15, l4 = lane >> 4;
    const int lofs = l4 * 8;
    const int j0 = blk * 16;
    const size_t r0 = (size_t)(j0 + l15);
    f32x4 ai[4][3];
    #pragma unroll
    for (int i = 0; i < 4; ++i)
      #pragma unroll
      for (int c = 0; c < 3; ++c) ai[i][c] = (f32x4){0,0,0,0};
    { // GIPb: c_t against second K-half of A3
      const int kw = 1024 + kq*256;
      const u16* W0 = p.A3 + (r0       )*2048 + kw + lofs;
      const u16* W1 = p.A3 + (r0 + 1024)*2048 + kw + lofs;
      const u16* W2 = p.A3 + (r0 + 2048)*2048 + kw + lofs;
      gemm3<8>(p.cb + (size_t)l15*DD + kq*256 + lofs, DD, W0, W1, W2, ai);
    }
    if (kq == 1) parkAcc48(LI0, ai, l15, l4, false);
    if (kq == 3) parkAcc48(LI1, ai, l15, l4, false);
    __syncthreads();
    if (kq == 0) parkAcc48(LI0, ai, l15, l4, true);
    if (kq == 2) parkAcc48(LI1, ai, l15, l4, true);
    __syncthreads();
    if (tid < 128) {
      const int b = tid >> 1, jjb = (tid & 1) * 8;
      const int spkc = p.spk[t*BB + b];
      const int spkn = (t+1 < TT) ? p.spk[(t+1)*BB + b] : spkc;
      float* prow = p.parties + (size_t)(b*2 + spkc)*DD;
      const float* orow = p.parties + (size_t)(b*2 + spkn)*DD;
      const float* Gia = ((t & 1) ? p.GIPa1 : p.GIPa0) + (size_t)b*G3;
      const float* Ghp = p.GHP + (size_t)b*G3;
      const float* i0 = LI0 + b*48; const float* i1 = LI1 + b*48;
      float qn8[8], qs8[8];
      #pragma unroll
      for (int i = 0; i < 8; ++i) {
        const int jj = jjb + i, j = j0 + jj;
        const float gi_r = Gia[j]      + i0[jj]    + i1[jj]    + p.bihp[j];
        const float gi_z = Gia[1024+j] + i0[16+jj] + i1[16+jj] + p.bihp[1024+j];
        const float gi_n = Gia[2048+j] + i0[32+jj] + i1[32+jj] + p.bihp[2048+j];
        const float gh_r = Ghp[j]      + p.bhhp[j];
        const float gh_z = Ghp[1024+j] + p.bhhp[1024+j];
        const float gh_n = Ghp[2048+j] + p.bhhp[2048+j];
        const float r_ = sigm(gi_r + gh_r);
        const float z_ = sigm(gi_z + gh_z);
        const float n_ = tanh_(gi_n + r_*gh_n);
        const float h  = prow[j];
        const float qv = (1.f - z_)*n_ + z_*h;
        prow[j] = qv;
        qn8[i] = qv;
        qs8[i] = (spkn == spkc) ? qv : orow[j];
      }
      bf16x8 qn, qs;
      #pragma unroll
      for (int i = 0; i < 8; ++i) { qn[i] = (short)f2b(qn8[i]); qs[i] = (short)f2b(qs8[i]); }
      *(bf16x8*)(p.qnewb + (size_t)b*DD + j0 + jjb) = qn;
      *(bf16x8*)(p.qselb + (size_t)b*DD + j0 + jjb) = qs;
    }
  } else {
    if (t + 1 < TT) {
      float* GIPn = ((t + 1) & 1) ? p.GIPa1 : p.GIPa0;
      gemm_frag(p.feat + (size_t)(t+1)*BB*DD, p.A3, 2048, 0, (blk-64)*64, GIPn, L);
    }
  }
}

// ---- prologue: GIPa(0) ----
__global__ void __launch_bounds__(256) kPre(DPar p) {
  __shared__ __align__(16) float red[4096];
  gemm_frag(p.feat, p.A3, 2048, 0, (int)blockIdx.x*64, p.GIPa0, red);
}

// ---- epilogue: emotion step 127 ----
__global__ void __launch_bounds__(256) kEpi(DPar p) {
  __shared__ __align__(16) char lds[49152];
  fusedE(p, TT, (int)blockIdx.x, lds);
}

// ---- setup: weight fp32 -> bf16 cast + state zero + speaker idx (every launch) ----
__global__ void setupK(const float* __restrict__ Wg, const float* __restrict__ Whg,
                       const float* __restrict__ Wp, const float* __restrict__ Whp,
                       const float* __restrict__ We, const float* __restrict__ Whe,
                       u16* A1, u16* A2, u16* A3, u16* A4, u16* A5, u16* A6,
                       float* parties, float* gf, float* ef,
                       u16* cb, u16* qselb, u16* qnewb, u16* eb0, u16* eb1,
                       const float* spkOH, int* spk) {
  long gid = (long)blockIdx.x*256 + threadIdx.x;
  if (gid < BB*2*DD) parties[gid] = 0.f;
  if (gid < BB*DD) {
    gf[gid] = 0.f; ef[gid] = 0.f;
    cb[gid] = 0; qselb[gid] = 0; qnewb[gid] = 0; eb0[gid] = 0; eb1[gid] = 0;
  }
  if (gid < TT*BB) spk[gid] = (spkOH[(size_t)gid*2 + 1] > 0.5f) ? 1 : 0;
  const long n1 = (long)G3*2048/4, n2 = (long)G3*1024/4;
  const long tot = 2*n1 + 4*n2;
  const long stride = (long)gridDim.x*256;
  for (long i = gid; i < tot; i += stride) {
    const float* src; u16* dst; long o = i;
    if (o < n1) { src = Wg;  dst = A1; }
    else { o -= n1;
      if (o < n2) { src = Whg; dst = A2; }
      else { o -= n2;
        if (o < n1) { src = Wp; dst = A3; }
        else { o -= n1;
          if (o < n2) { src = Whp; dst = A4; }
          else { o -= n2;
            if (o < n2) { src = We; dst = A5; }
            else { o -= n2; src = Whe; dst = A6; }
          }
        }
      }
    }
    f32x4 v = *(const f32x4*)(src + o*4);
    s16x4 w;
    w[0] = (short)f2b(v[0]); w[1] = (short)f2b(v[1]);
    w[2] = (short)f2b(v[2]); w[3] = (short)f2b(v[3]);
    *(s16x4*)(dst + o*4) = w;
  }
}

extern "C" void kernel_launch(void* const* d_in, const int* in_sizes, int n_in,
                              void* d_out, int out_size, void* d_ws, size_t ws_size,
                              hipStream_t stream) {
  const float* feat  = (const float*)d_in[0];
  const float* spkOH = (const float*)d_in[1];
  const float* Wih_g = (const float*)d_in[2];
  const float* Whh_g = (const float*)d_in[3];
  const float* bih_g = (const float*)d_in[4];
  const float* bhh_g = (const float*)d_in[5];
  const float* Wih_p = (const float*)d_in[6];
  const float* Whh_p = (const float*)d_in[7];
  const float* bih_p = (const float*)d_in[8];
  const float* bhh_p = (const float*)d_in[9];
  const float* Wih_e = (const float*)d_in[10];
  const float* Whh_e = (const float*)d_in[11];
  const float* bih_e = (const float*)d_in[12];
  const float* bhh_e = (const float*)d_in[13];
  const float* watt  = (const float*)d_in[14];

  char* w = (char*)d_ws;
  auto alloc = [&](size_t bytes) -> char* {
    char* r = w; w += (bytes + 255) & ~(size_t)255; return r;
  };
  u16* ghist = (u16*)alloc((size_t)TT*BB*DD*2);
  float* scoresP = (float*)alloc((size_t)TT*64*BB*4);
  u16* cb    = (u16*)alloc((size_t)BB*DD*2);
  u16* qselb = (u16*)alloc((size_t)BB*DD*2);
  u16* qnewb = (u16*)alloc((size_t)BB*DD*2);
  u16* eb0   = (u16*)alloc((size_t)BB*DD*2);
  u16* eb1   = (u16*)alloc((size_t)BB*DD*2);
  float* parties = (float*)alloc((size_t)BB*2*DD*4);
  float* gf  = (float*)alloc((size_t)BB*DD*4);
  float* ef  = (float*)alloc((size_t)BB*DD*4);
  float* GIPa0 = (float*)alloc((size_t)BB*G3*4);
  float* GIPa1 = (float*)alloc((size_t)BB*G3*4);
  float* GHP   = (float*)alloc((size_t)BB*G3*4);
  int* spk    = (int*)alloc((size_t)TT*BB*4);
  u16* A1 = (u16*)alloc((size_t)G3*2048*2);
  u16* A2 = (u16*)alloc((size_t)G3*1024*2);
  u16* A3 = (u16*)alloc((size_t)G3*2048*2);
  u16* A4 = (u16*)alloc((size_t)G3*1024*2);
  u16* A5 = (u16*)alloc((size_t)G3*1024*2);
  u16* A6 = (u16*)alloc((size_t)G3*1024*2);
  const size_t need = (size_t)(w - (char*)d_ws);   // ~73.5 MB < proven 75.5 MB bound
  if (ws_size < need) return;   // fail validation visibly rather than fault

  hipLaunchKernelGGL(setupK, dim3(2048), dim3(256), 0, stream,
                     Wih_g, Whh_g, Wih_p, Whh_p, Wih_e, Whh_e,
                     A1, A2, A3, A4, A5, A6,
                     parties, gf, ef, cb, qselb, qnewb, eb0, eb1, spkOH, spk);

  DPar p;
  p.A1 = A1; p.A2 = A2; p.A3 = A3; p.A4 = A4; p.A5 = A5; p.A6 = A6;
  p.feat = feat;
  p.ghist = ghist; p.cb = cb; p.qselb = qselb; p.qnewb = qnewb; p.eb0 = eb0; p.eb1 = eb1;
  p.scoresP = scoresP; p.parties = parties; p.gf = gf; p.ef = ef;
  p.GIPa0 = GIPa0; p.GIPa1 = GIPa1; p.GHP = GHP;
  p.bihg = bih_g; p.bhhg = bhh_g; p.bihp = bih_p; p.bhhp = bhh_p;
  p.bihe = bih_e; p.bhhe = bhh_e; p.watt = watt;
  p.spk = spk; p.out = (float*)d_out;

  hipLaunchKernelGGL(kPre, dim3(48), dim3(256), 0, stream, p);
  for (int t = 0; t < TT; ++t) {
    hipLaunchKernelGGL(k1_step, dim3(240), dim3(256), 0, stream, p, t);
    hipLaunchKernelGGL(k2_step, dim3(112), dim3(256), 0, stream, p, t);
  }
  hipLaunchKernelGGL(kEpi, dim3(64), dim3(256), 0, stream, p);
}